// Round 1
// baseline (912.832 us; speedup 1.0000x reference)
//
#include <hip/hip_runtime.h>
#include <math.h>

// Problem: B=4, N=128, H=W=32, C=64.
// out[b][j][n] = sigmoid( wl[j,:] . mean_{h,w} MLP(x(b,n,h,w)) + bl[j] )
// MLP: 5 leaky-relu layers; layer1 input = [img0,img1,img2, h/31, w/31, cx, cy].
//
// Strategy: 1 block per (b,n) [512 blocks, 256 thr], 4 pixels/thread.
// Per-thread activations in registers (static indexing only); per-layer
// outputs round-trip through a private LDS column (no barriers needed).
// Weights are wave-uniform -> scalar loads (SGPR operand to v_fmac_f32).

#define NEG_SLOPE 0.1f

__global__ __launch_bounds__(256, 2) void mlp_field_kernel(
    const float* __restrict__ image,   // [4,3,32,32]
    const float* __restrict__ coords,  // [4,128,2]
    const float* __restrict__ w1, const float* __restrict__ b1,  // [64,7],[64]
    const float* __restrict__ w2, const float* __restrict__ b2,  // [64,64],[64]
    const float* __restrict__ w3, const float* __restrict__ b3,
    const float* __restrict__ w4, const float* __restrict__ b4,
    const float* __restrict__ w5, const float* __restrict__ b5,
    const float* __restrict__ wl, const float* __restrict__ bl,  // [3,64],[3]
    float* __restrict__ out)           // [4,3,128]
{
    __shared__ float act[64][256];   // [channel][thread] — thread-private columns
    __shared__ float red[3][4];      // final cross-wave reduction

    const int tid = threadIdx.x;
    const int bn  = blockIdx.x;      // b*128 + n
    const int b   = bn >> 7;
    const int n   = bn & 127;

    const float cx = coords[2*bn + 0];
    const float cy = coords[2*bn + 1];
    const float* img = image + b * 3 * 1024;

    float t0 = 0.f, t1 = 0.f, t2 = 0.f;   // sum over pixels of wl . x

    #pragma unroll 1
    for (int k = 0; k < 4; ++k) {
        const int hw = tid + (k << 8);          // 0..1023
        const int h  = hw >> 5;
        const int w  = hw & 31;
        const float i0 = img[hw];
        const float i1 = img[1024 + hw];
        const float i2 = img[2048 + hw];
        const float pr = (float)h * (1.0f / 31.0f);
        const float pc = (float)w * (1.0f / 31.0f);

        // ---- layer 1: 7 -> 64 ----
        #pragma unroll 1
        for (int og = 0; og < 8; ++og) {
            #pragma unroll
            for (int j = 0; j < 8; ++j) {
                const int o = og * 8 + j;
                const float* wr = w1 + o * 7;   // uniform address -> s_load
                float a = b1[o]
                        + wr[0] * i0 + wr[1] * i1 + wr[2] * i2
                        + wr[3] * pr + wr[4] * pc
                        + wr[5] * cx + wr[6] * cy;
                act[o][tid] = (a >= 0.f) ? a : NEG_SLOPE * a;
            }
        }

        float x[64];
        #pragma unroll
        for (int c = 0; c < 64; ++c) x[c] = act[c][tid];

        // ---- hidden layers 2..5: 64 -> 64 ----
        #pragma unroll 1
        for (int L = 0; L < 4; ++L) {
            const float* W  = (L == 0) ? w2 : (L == 1) ? w3 : (L == 2) ? w4 : w5;
            const float* Bv = (L == 0) ? b2 : (L == 1) ? b3 : (L == 2) ? b4 : b5;

            #pragma unroll 1
            for (int og = 0; og < 8; ++og) {
                float acc[8];
                #pragma unroll
                for (int j = 0; j < 8; ++j) acc[j] = Bv[og * 8 + j];
                #pragma unroll
                for (int c = 0; c < 64; ++c) {
                    const float xc = x[c];
                    #pragma unroll
                    for (int j = 0; j < 8; ++j)
                        acc[j] += W[(og * 8 + j) * 64 + c] * xc;  // SGPR weight
                }
                #pragma unroll
                for (int j = 0; j < 8; ++j) {
                    const float a = acc[j];
                    act[og * 8 + j][tid] = (a >= 0.f) ? a : NEG_SLOPE * a;
                }
            }
            #pragma unroll
            for (int c = 0; c < 64; ++c) x[c] = act[c][tid];
        }

        // ---- head partial: wl . x (mean deferred) ----
        float s0 = 0.f, s1 = 0.f, s2 = 0.f;
        #pragma unroll
        for (int c = 0; c < 64; ++c) {
            s0 += wl[0 * 64 + c] * x[c];
            s1 += wl[1 * 64 + c] * x[c];
            s2 += wl[2 * 64 + c] * x[c];
        }
        t0 += s0; t1 += s1; t2 += s2;
    }

    // ---- reduce over 256 threads (4 waves of 64) ----
    #pragma unroll
    for (int off = 32; off > 0; off >>= 1) {
        t0 += __shfl_down(t0, off, 64);
        t1 += __shfl_down(t1, off, 64);
        t2 += __shfl_down(t2, off, 64);
    }
    const int wave = tid >> 6;
    const int lane = tid & 63;
    if (lane == 0) { red[0][wave] = t0; red[1][wave] = t1; red[2][wave] = t2; }
    __syncthreads();
    if (tid < 3) {
        const float s = red[tid][0] + red[tid][1] + red[tid][2] + red[tid][3];
        const float z = s * (1.0f / 1024.0f) + bl[tid];
        out[(b * 3 + tid) * 128 + n] = 1.0f / (1.0f + expf(-z));
    }
}

extern "C" void kernel_launch(void* const* d_in, const int* in_sizes, int n_in,
                              void* d_out, int out_size, void* d_ws, size_t ws_size,
                              hipStream_t stream) {
    const float* image  = (const float*)d_in[0];
    const float* coords = (const float*)d_in[1];
    const float* w1 = (const float*)d_in[2];
    const float* b1 = (const float*)d_in[3];
    const float* w2 = (const float*)d_in[4];
    const float* b2 = (const float*)d_in[5];
    const float* w3 = (const float*)d_in[6];
    const float* b3 = (const float*)d_in[7];
    const float* w4 = (const float*)d_in[8];
    const float* b4 = (const float*)d_in[9];
    const float* w5 = (const float*)d_in[10];
    const float* b5 = (const float*)d_in[11];
    const float* wl = (const float*)d_in[12];
    const float* bl = (const float*)d_in[13];
    float* out = (float*)d_out;

    mlp_field_kernel<<<dim3(512), dim3(256), 0, stream>>>(
        image, coords, w1, b1, w2, b2, w3, b3, w4, b4, w5, b5, wl, bl, out);
}

// Round 2
// 134.620 us; speedup vs baseline: 6.7808x; 6.7808x over previous
//
#include <hip/hip_runtime.h>
#include <math.h>

// B=4, N=128, H=W=32, C=64.  out[b][j][n] = sigmoid(wl[j,:] . mean_hw MLP(...) + bl[j])
//
// MFMA formulation: per (b,n), layers 2..5 are 64x64 GEMMs over 1024 pixel
// columns -> v_mfma_f32_16x16x32_bf16, M=64(ch) x N=32(px) x K=64 tiles.
// Layer 1 (7->64) is the same MFMA with K=32 zero-padded.
// 1 block per (b,n): 512 blocks x 256 thr (4 waves); wave = 8 x 32-px tiles.
// Weights held as A-frags in VGPRs (loaded once per wave, L1/L2-resident).
// Activation layout transform C-layout -> B-layout via 4KB/wave LDS:
//   C: col=lane&15, row=(lane>>4)*4+reg   [m89-verified]
//   A/B: n=lane&15, k=(lane>>4)*8+j        [m120-verified]
//   => regs r=0..3 land j-contiguous: one ds_write_b64 per 16x16 tile.

typedef float  f32x4  __attribute__((ext_vector_type(4)));
typedef f32x4  f32x4a __attribute__((may_alias));
typedef __bf16 bf16x8 __attribute__((ext_vector_type(8)));
typedef bf16x8 bf16x8a __attribute__((may_alias));
typedef __bf16 bf16x4 __attribute__((ext_vector_type(4)));
typedef bf16x4 bf16x4a __attribute__((may_alias));
typedef float  floata __attribute__((may_alias));

#define MFMA16(a, b, c) __builtin_amdgcn_mfma_f32_16x16x32_bf16((a), (b), (c), 0, 0, 0)

__global__ __launch_bounds__(256, 2) void mlp_mfma_kernel(
    const float* __restrict__ image,   // [4,3,32,32]
    const float* __restrict__ coords,  // [4,128,2]
    const float* __restrict__ w1, const float* __restrict__ b1,   // [64,7],[64]
    const float* __restrict__ w2, const float* __restrict__ b2,   // [64,64],[64]
    const float* __restrict__ w3, const float* __restrict__ b3,
    const float* __restrict__ w4, const float* __restrict__ b4,
    const float* __restrict__ w5, const float* __restrict__ b5,
    const float* __restrict__ wl, const float* __restrict__ bl,   // [3,64],[3]
    float* __restrict__ out)           // [4,3,128]
{
    __shared__ __align__(16) __bf16 Xs[4][2048];   // 4KB per wave: B-frag ping-pong

    const int tid  = threadIdx.x;
    const int wave = tid >> 6;
    const int lane = tid & 63;
    const int c15  = lane & 15;
    const int q    = lane >> 4;
    const int bn   = blockIdx.x;
    const int b    = bn >> 7;

    __bf16* Xw = &Xs[wave][0];

    const float cx = coords[2 * bn + 0];
    const float cy = coords[2 * bn + 1];

    // ---- preload W2..W5 as A-fragments in VGPRs (bf16x8 per [layer][mt][ks])
    const float* Ws[4] = {w2, w3, w4, w5};
    const float* Bs[4] = {b2, b3, b4, b5};
    bf16x8 wf[4][4][2];
    #pragma unroll
    for (int l = 0; l < 4; ++l)
        #pragma unroll
        for (int mt = 0; mt < 4; ++mt)
            #pragma unroll
            for (int ks = 0; ks < 2; ++ks) {
                const float* src = Ws[l] + (mt * 16 + c15) * 64 + ks * 32 + q * 8;
                f32x4 lo = *(const f32x4a*)src;
                f32x4 hi = *(const f32x4a*)(src + 4);
                bf16x8 f;
                f[0] = (__bf16)lo[0]; f[1] = (__bf16)lo[1];
                f[2] = (__bf16)lo[2]; f[3] = (__bf16)lo[3];
                f[4] = (__bf16)hi[0]; f[5] = (__bf16)hi[1];
                f[6] = (__bf16)hi[2]; f[7] = (__bf16)hi[3];
                wf[l][mt][ks] = f;
            }

    // ---- W1 A-frags: K=32 zero-padded (valid only q==0, k<7)
    const float qm = (q == 0) ? 1.0f : 0.0f;
    bf16x8 w1f[4];
    #pragma unroll
    for (int mt = 0; mt < 4; ++mt) {
        const int o = mt * 16 + c15;
        bf16x8 f;
        #pragma unroll
        for (int j = 0; j < 7; ++j)
            f[j] = (__bf16)(qm * w1[o * 7 + j]);
        f[7] = (__bf16)0.0f;
        w1f[mt] = f;
    }

    const float* img = image + b * 3072;
    // per-lane halfword offset of the transform write
    const int lane_woff = c15 * 8 + (q >> 1) * 128 + (q & 1) * 4;

    f32x4 pool[4];
    #pragma unroll
    for (int mt = 0; mt < 4; ++mt) pool[mt] = (f32x4){0.f, 0.f, 0.f, 0.f};

    const int wbase = wave * 256;

    // epilogue: leaky + cvt bf16 + C->B layout transform into LDS
    auto store_x = [&](f32x4 (&acc)[4][2]) {
        #pragma unroll
        for (int mt = 0; mt < 4; ++mt)
            #pragma unroll
            for (int nt = 0; nt < 2; ++nt) {
                f32x4 a = acc[mt][nt];
                bf16x4 p;
                #pragma unroll
                for (int r = 0; r < 4; ++r) {
                    float v = fmaxf(a[r], 0.1f * a[r]);   // leaky (slope<1)
                    p[r] = (__bf16)v;
                }
                const int off = (nt * 2 + (mt >> 1)) * 512 + (mt & 1) * 256 + lane_woff;
                *(bf16x4a*)&Xw[off] = p;
            }
    };

    #pragma unroll 1
    for (int t = 0; t < 8; ++t) {
        // ---- layer 1: build feature B-frags directly in registers
        bf16x8 bft[2];
        #pragma unroll
        for (int nt = 0; nt < 2; ++nt) {
            const int hw = wbase + t * 32 + nt * 16 + c15;
            const float i0 = img[hw];
            const float i1 = img[1024 + hw];
            const float i2 = img[2048 + hw];
            bf16x8 f;
            f[0] = (__bf16)(qm * i0);
            f[1] = (__bf16)(qm * i1);
            f[2] = (__bf16)(qm * i2);
            f[3] = (__bf16)(qm * (float)(hw >> 5) * (1.0f / 31.0f));
            f[4] = (__bf16)(qm * (float)(hw & 31) * (1.0f / 31.0f));
            f[5] = (__bf16)(qm * cx);
            f[6] = (__bf16)(qm * cy);
            f[7] = (__bf16)0.0f;
            bft[nt] = f;
        }

        f32x4 acc[4][2];
        #pragma unroll
        for (int mt = 0; mt < 4; ++mt) {
            f32x4 bv = *(const f32x4a*)(b1 + mt * 16 + 4 * q);
            acc[mt][0] = bv; acc[mt][1] = bv;
        }
        #pragma unroll
        for (int mt = 0; mt < 4; ++mt)
            #pragma unroll
            for (int nt = 0; nt < 2; ++nt)
                acc[mt][nt] = MFMA16(w1f[mt], bft[nt], acc[mt][nt]);
        store_x(acc);

        // ---- layers 2..5
        #pragma unroll
        for (int l = 0; l < 4; ++l) {
            bf16x8 bf[2][2];
            #pragma unroll
            for (int nt = 0; nt < 2; ++nt)
                #pragma unroll
                for (int ks = 0; ks < 2; ++ks)
                    bf[nt][ks] = *(const bf16x8a*)&Xw[((nt * 2 + ks) * 64 + lane) * 8];
            #pragma unroll
            for (int mt = 0; mt < 4; ++mt) {
                f32x4 bv = *(const f32x4a*)(Bs[l] + mt * 16 + 4 * q);
                acc[mt][0] = bv; acc[mt][1] = bv;
            }
            #pragma unroll
            for (int mt = 0; mt < 4; ++mt)
                #pragma unroll
                for (int nt = 0; nt < 2; ++nt)
                    #pragma unroll
                    for (int ks = 0; ks < 2; ++ks)
                        acc[mt][nt] = MFMA16(wf[l][mt][ks], bf[nt][ks], acc[mt][nt]);
            if (l < 3) {
                store_x(acc);
            } else {
                // layer 5: leaky + pool accumulate (fp32)
                #pragma unroll
                for (int mt = 0; mt < 4; ++mt)
                    #pragma unroll
                    for (int nt = 0; nt < 2; ++nt) {
                        f32x4 a = acc[mt][nt];
                        #pragma unroll
                        for (int r = 0; r < 4; ++r)
                            pool[mt][r] += fmaxf(a[r], 0.1f * a[r]);
                    }
            }
        }
    }

    // ---- pool partials -> float view of (now free) X region: [ch][col16]
    floata* Xf = (floata*)Xw;
    #pragma unroll
    for (int mt = 0; mt < 4; ++mt)
        #pragma unroll
        for (int r = 0; r < 4; ++r)
            Xf[(mt * 16 + 4 * q + r) * 16 + c15] = pool[mt][r];

    __syncthreads();

    // ---- block reduce (4 waves x 16 cols) + head + sigmoid (wave 0 only)
    if (tid < 64) {
        const int c = tid;
        float s = 0.0f;
        #pragma unroll
        for (int w = 0; w < 4; ++w) {
            const floata* P = (const floata*)&Xs[w][0];
            #pragma unroll
            for (int c4 = 0; c4 < 4; ++c4) {
                f32x4 v = *(const f32x4a*)&P[c * 16 + c4 * 4];
                s += v[0] + v[1] + v[2] + v[3];
            }
        }
        const float p = s * (1.0f / 1024.0f);
        float s0 = wl[c] * p;
        float s1 = wl[64 + c] * p;
        float s2 = wl[128 + c] * p;
        #pragma unroll
        for (int off = 32; off > 0; off >>= 1) {
            s0 += __shfl_down(s0, off, 64);
            s1 += __shfl_down(s1, off, 64);
            s2 += __shfl_down(s2, off, 64);
        }
        if (c == 0) {
            const int n = bn & 127;
            out[(b * 3 + 0) * 128 + n] = 1.0f / (1.0f + expf(-(bl[0] + s0)));
            out[(b * 3 + 1) * 128 + n] = 1.0f / (1.0f + expf(-(bl[1] + s1)));
            out[(b * 3 + 2) * 128 + n] = 1.0f / (1.0f + expf(-(bl[2] + s2)));
        }
    }
}

extern "C" void kernel_launch(void* const* d_in, const int* in_sizes, int n_in,
                              void* d_out, int out_size, void* d_ws, size_t ws_size,
                              hipStream_t stream) {
    const float* image  = (const float*)d_in[0];
    const float* coords = (const float*)d_in[1];
    const float* w1 = (const float*)d_in[2];
    const float* b1 = (const float*)d_in[3];
    const float* w2 = (const float*)d_in[4];
    const float* b2 = (const float*)d_in[5];
    const float* w3 = (const float*)d_in[6];
    const float* b3 = (const float*)d_in[7];
    const float* w4 = (const float*)d_in[8];
    const float* b4 = (const float*)d_in[9];
    const float* w5 = (const float*)d_in[10];
    const float* b5 = (const float*)d_in[11];
    const float* wl = (const float*)d_in[12];
    const float* bl = (const float*)d_in[13];
    float* out = (float*)d_out;

    mlp_mfma_kernel<<<dim3(512), dim3(256), 0, stream>>>(
        image, coords, w1, b1, w2, b2, w3, b3, w4, b4, w5, b5, wl, bl, out);
}